// Round 9
// baseline (265.841 us; speedup 1.0000x reference)
//
#include <hip/hip_runtime.h>

#define EPSF 1e-12f
constexpr int BB = 2;
constexpr int PP = 8192;
constexpr int VV = 4098;
constexpr int FF = 8192;

constexpr int SLOW_F4 = 5;            // verbatim record: 5 x float4
constexpr int SCR_ST = 12;            // screen record: 6 f2 per tri-pair (floats)
constexpr int RST_ST = 40;            // rest record: 20 f2 per tri-pair (floats)
constexpr int PTS_PER_BLOCK = 256;    // 1 point/thread x 256 threads
constexpr int NSLICES = 16;
constexpr int CHUNK_T = FF / NSLICES; // 512 tris/block = 8 mask words

typedef float f2 __attribute__((ext_vector_type(2)));

__device__ __forceinline__ f2 vfma(f2 a, f2 b, f2 c) {
#if __has_builtin(__builtin_elementwise_fma)
    return __builtin_elementwise_fma(a, b, c);
#else
    return (f2){fmaf(a.x, b.x, c.x), fmaf(a.y, b.y, c.y)};
#endif
}
__device__ __forceinline__ f2 vmin2(f2 a, f2 b) { return __builtin_elementwise_min(a, b); }
__device__ __forceinline__ f2 vmax2(f2 a, f2 b) { return __builtin_elementwise_max(a, b); }
__device__ __forceinline__ f2 bc(float s) { return (f2){s, s}; }

// monotone float<->uint for atomicMin/Max on y-extent
__device__ __forceinline__ unsigned int fkey(float f) {
    unsigned int u = __float_as_uint(f);
    return (u >> 31) ? ~u : (u | 0x80000000u);
}
__device__ __forceinline__ float funkey(unsigned int k) {
    unsigned int u = (k >> 31) ? (k ^ 0x80000000u) : ~k;
    return __uint_as_float(u);
}

// ---------------------------------------------------------------------------
// Kernel 1: split pair-interleaved records + sliver bitmask + inits.
// SCREEN per tri (5+pad): nx,ny,nz,kan*,inn  -> dq = ((n.p - kan))^2 * inn is
//   a rigorous LOWER bound on the fast-path distance (all candidates lie in
//   the triangle plane). Sliver poisoning kan*=+inf => dq=+inf (never passes
//   the screen; phase B handles exactly).
// REST per tri (19+pad): ab,ka1, ac,ka2, a,aa*, ab2,ac2,abac,bc2,
//   iab2,iac2,ibc2. aa*=+inf for slivers (paired-half safety).
// Both stored interleaved per tri-PAIR: arr[pair*stride + 2*c + (idx&1)].
// ---------------------------------------------------------------------------
__global__ __launch_bounds__(256) void precompute_kernel(
    const float* __restrict__ verts, const int* __restrict__ faces,
    float* __restrict__ scr, float* __restrict__ rest,
    float4* __restrict__ slowrec, unsigned long long* __restrict__ mask,
    unsigned int* __restrict__ minD,
    float* __restrict__ sums, unsigned int* __restrict__ ykmin,
    unsigned int* __restrict__ ykmax)
{
    int idx = blockIdx.x * 256 + threadIdx.x;   // grid exactly covers BB*FF
    if (idx < BB) { sums[idx] = 0.0f; ykmin[idx] = 0xFFFFFFFFu; ykmax[idx] = 0u; }
    if (idx < BB * PP) minD[idx] = 0x7F800000u; // +inf
    if (idx >= BB * FF) return;

    int b = idx / FF;
    const float* vb = verts + (size_t)b * VV * 3;
    int i0 = faces[idx * 3 + 0];
    int i1 = faces[idx * 3 + 1];
    int i2 = faces[idx * 3 + 2];

    float ax = vb[i0*3+0], ay = vb[i0*3+1], az = vb[i0*3+2];
    float bx = vb[i1*3+0], by = vb[i1*3+1], bz = vb[i1*3+2];
    float cx = vb[i2*3+0], cy = vb[i2*3+1], cz = vb[i2*3+2];

    float abx = bx-ax, aby = by-ay, abz = bz-az;
    float acx = cx-ax, acy = cy-ay, acz = cz-az;
    float bcx = cx-bx, bcy = cy-by, bcz = cz-bz;

    {   // slow record (read only for flagged tris)
        float4* t = slowrec + (size_t)idx * SLOW_F4;
        t[0] = make_float4(ax, ay, az, abx);
        t[1] = make_float4(bx, by, bz, aby);
        t[2] = make_float4(cx, cy, cz, abz);
        t[3] = make_float4(acx, acy, acz, bcx);
        t[4] = make_float4(bcy, bcz, 0.0f, 0.0f);
    }

    float nx = aby*acz - abz*acy;
    float ny = abz*acx - abx*acz;
    float nz = abx*acy - aby*acx;

    float ka1  = abx*ax + aby*ay + abz*az;
    float ka2  = acx*ax + acy*ay + acz*az;
    float kan  = nx*ax + ny*ay + nz*az;
    float aa   = ax*ax + ay*ay + az*az;
    float abac = abx*acx + aby*acy + abz*acz;

    float ab2 = abx*abx + aby*aby + abz*abz;
    float ac2 = acx*acx + acy*acy + acz*acz;
    float bc2 = bcx*bcx + bcy*bcy + bcz*bcz;
    float nn  = nx*nx + ny*ny + nz*nz;

    float inv_ab2 = 1.0f / fmaxf(ab2, EPSF);
    float inv_ac2 = 1.0f / fmaxf(ac2, EPSF);
    float inv_bc2 = 1.0f / fmaxf(bc2, EPSF);
    float inv_nn  = 1.0f / fmaxf(nn,  EPSF);

    // sliver/degenerate classifier: sin^2(angle at a) <= 3e-2 or tiny edges
    bool slowtri = !((nn > 0.03f * (ab2 * ac2)) &&
                     (ab2 > 1e-4f) && (ac2 > 1e-4f) && (bc2 > 1e-4f));

    unsigned long long mb = __ballot(slowtri);
    if ((threadIdx.x & 63) == 0) mask[idx >> 6] = mb;

    float INF = __uint_as_float(0x7F800000u);
    int half = idx & 1;
    {
        float* s = scr + (size_t)(idx >> 1) * SCR_ST + half;
        s[0] = nx; s[2] = ny; s[4] = nz;
        s[6] = slowtri ? INF : kan;
        s[8] = inv_nn; s[10] = 0.0f;
    }
    {
        float rv[19] = { abx, aby, abz, ka1,
                         acx, acy, acz, ka2,
                         ax,  ay,  az,  slowtri ? INF : aa,
                         ab2, ac2, abac, bc2,
                         inv_ab2, inv_ac2, inv_bc2 };
        float* r = rest + (size_t)(idx >> 1) * RST_ST + half;
#pragma unroll
        for (int c = 0; c < 19; ++c) r[2*c] = rv[c];
        r[38] = 0.0f;
    }
}

// ---------------------------------------------------------------------------
// Verbatim fp32 port (bit-exact vs numpy) — slivers only. Proven in R3.
// ---------------------------------------------------------------------------
__device__ __forceinline__ float tri_d2(
    float px, float py, float pz,
    float4 R0, float4 R1, float4 R2, float4 R3, float4 R4)
{
#pragma clang fp contract(off)
    float ax = R0.x, ay = R0.y, az = R0.z;
    float bx = R1.x, by = R1.y, bz = R1.z;
    float cx = R2.x, cy = R2.y, cz = R2.z;
    float abx = R0.w, aby = R1.w, abz = R2.w;
    float acx = R3.x, acy = R3.y, acz = R3.z;
    float bcx = R3.w, bcy = R4.x, bcz = R4.y;

    float apx = px - ax, apy = py - ay, apz = pz - az;
    float d1 = (abx*apx + aby*apy) + abz*apz;
    float d2 = (acx*apx + acy*apy) + acz*apz;
    float bpx = px - bx, bpy = py - by, bpz = pz - bz;
    float d3 = (abx*bpx + aby*bpy) + abz*bpz;
    float d4 = (acx*bpx + acy*bpy) + acz*bpz;
    float cqx = px - cx, cqy = py - cy, cqz = pz - cz;
    float d5 = (abx*cqx + aby*cqy) + abz*cqz;
    float d6 = (acx*cqx + acy*cqy) + acz*cqz;

    float va = d3*d6 - d5*d4;
    float vb = d5*d2 - d1*d6;
    float vc = d1*d4 - d3*d2;
    float u43 = d4 - d3;
    float u56 = d5 - d6;

    bool c1 = (d1 <= 0.0f) && (d2 <= 0.0f);
    bool c2 = (d3 >= 0.0f) && (d4 <= d3);
    bool c3 = (d6 >= 0.0f) && (d5 <= d6);
    bool c4 = (vc <= 0.0f) && (d1 >= 0.0f) && (d3 <= 0.0f);
    bool c5 = (vb <= 0.0f) && (d2 >= 0.0f) && (d6 <= 0.0f);
    bool c6 = (va <= 0.0f) && (u43 >= 0.0f) && (u56 >= 0.0f);

    int reg = c1 ? 0 : (c2 ? 1 : (c3 ? 2 : (c4 ? 3 : (c5 ? 4 : (c6 ? 5 : 6)))));

    float denom = fmaxf((va + vb) + vc, EPSF);
    float den1 = (reg == 3) ? fmaxf(d1 - d3, EPSF)
               : (reg == 5) ? fmaxf(u43 + u56, EPSF)
               : (reg == 6) ? denom : 1.0f;
    float num1 = (reg == 3) ? d1
               : (reg == 5) ? u43
               : (reg == 6) ? vb : 0.0f;
    float den2 = (reg == 4) ? fmaxf(d2 - d6, EPSF)
               : (reg == 6) ? denom : 1.0f;
    float num2 = (reg == 4) ? d2
               : (reg == 6) ? vc : 0.0f;
    float s = num1 / den1;
    float t = num2 / den2;

    bool useB = (reg == 1) || (reg == 5);
    bool useC = (reg == 2);
    float basex = useB ? bx : (useC ? cx : ax);
    float basey = useB ? by : (useC ? cy : ay);
    float basez = useB ? bz : (useC ? cz : az);
    bool e1bc = (reg == 5);
    float e1x = e1bc ? bcx : abx;
    float e1y = e1bc ? bcy : aby;
    float e1z = e1bc ? bcz : abz;

    float cpx = (basex + e1x*s) + acx*t;
    float cpy = (basey + e1y*s) + acy*t;
    float cpz = (basez + e1z*s) + acz*t;
    float rx = px - cpx, ry = py - cpy, rz = pz - cpz;
    return (rx*rx + ry*ry) + rz*rz;
}

// ---------------------------------------------------------------------------
// Kernel 2: 1 point/thread, 512 tris/block, running-min + wave-vote screen.
// Per tri-pair: plane-dist lower bound dq (7 packed instrs); full eval (~47)
// only if ANY lane's dq beats its running min. dq is reused as dIN on pass.
// ---------------------------------------------------------------------------
__global__ __launch_bounds__(256) void dist_kernel(
    const float* __restrict__ pts, const f2* __restrict__ scr,
    const f2* __restrict__ rest, const float4* __restrict__ sa,
    const unsigned long long* __restrict__ mask, unsigned int* __restrict__ minD)
{
    const float INF = __uint_as_float(0x7F800000u);
    int tid   = threadIdx.x;
    int pg    = blockIdx.x;        // 0 .. 63
    int slice = blockIdx.y;        // 0 .. 15

    int b = pg / (PP / PTS_PER_BLOCK);   // 32 point-groups per batch
    int p = pg * PTS_PER_BLOCK + tid;

    float PXs = pts[p*3+0], PYs = pts[p*3+1], PZs = pts[p*3+2];
    f2 X = bc(PXs), Y = bc(PYs), Z = bc(PZs);
    f2 W = vfma(X, X, vfma(Y, Y, Z * Z));
    f2 m = bc(INF);

    int t0 = b * FF + slice * CHUNK_T;
    const f2* sc = scr + (size_t)(t0 >> 1) * (SCR_ST / 2);
    const f2* rc = rest + (size_t)(t0 >> 1) * (RST_ST / 2);

    for (int tp = 0; tp < CHUNK_T / 2; ++tp) {
        f2 nx = sc[0], ny = sc[1], nz = sc[2], kan = sc[3], inn = sc[4];
        sc += SCR_ST / 2;

        f2 sn  = vfma(nx, X, vfma(ny, Y, nz * Z));
        f2 tpn = sn - kan;                   // -inf if poisoned
        f2 dq  = (tpn * tpn) * inn;          // +inf if poisoned (lower bound)
        float mm = fminf(m.x, m.y);

        if (__ballot((dq.x < mm) || (dq.y < mm))) {
            f2 abx=rc[0], aby=rc[1], abz=rc[2], ka1=rc[3];
            f2 acx=rc[4], acy=rc[5], acz=rc[6], ka2=rc[7];
            f2 ax=rc[8],  ay=rc[9],  az=rc[10], aa=rc[11];
            f2 ab2=rc[12], ac2=rc[13], abac=rc[14], bc2=rc[15];
            f2 iab2=rc[16], iac2=rc[17], ibc2=rc[18];

            f2 sab = vfma(abx, X, vfma(aby, Y, abz * Z));
            f2 sac = vfma(acx, X, vfma(acy, Y, acz * Z));
            f2 adp = vfma(ax,  X, vfma(ay,  Y, az  * Z));

            f2 d1 = sab - ka1, d2 = sac - ka2;
            f2 d3 = d1 - ab2, d4 = d2 - abac;
            f2 d5 = d1 - abac, d6 = d2 - ac2;

            f2 ap2 = vfma(bc(-2.0f), adp, W) + aa;   // +inf if poisoned
            f2 bp2 = vfma(bc(-2.0f), d1, ap2) + ab2;

            f2 sA = vmin2(vmax2(d1 * iab2, bc(0.0f)), bc(1.0f));
            f2 dAB = vfma(-sA, vfma(-sA, ab2, d1 + d1), ap2);
            f2 sC = vmin2(vmax2(d2 * iac2, bc(0.0f)), bc(1.0f));
            f2 dAC = vfma(-sC, vfma(-sC, ac2, d2 + d2), ap2);
            f2 u43 = d4 - d3;
            f2 sB = vmin2(vmax2(u43 * ibc2, bc(0.0f)), bc(1.0f));
            f2 dBC = vfma(-sB, vfma(-sB, bc2, u43 + u43), bp2);

            f2 va = vfma(d3, d6, -(d5 * d4));
            f2 vb = vfma(d5, d2, -(d1 * d6));
            f2 vc = vfma(d1, d4, -(d3 * d2));
            f2 mv = vmin2(vmin2(va, vb), vc);
            // branchless gate: mv>=0 -> dq; mv<0 -> dq + |mv|*1e30 (as mv->0-
            // the projection hits the boundary so dq -> true dist: safe)
            f2 dI = vfma(vmin2(mv, bc(0.0f)), bc(-1e30f), dq);

            m = vmin2(m, vmin2(vmin2(dAB, dAC), vmin2(dBC, dI)));
        }
        rc += RST_ST / 2;
    }

    // Phase B: bit-exact eval for flagged slivers (8 mask words per block)
#pragma unroll
    for (int w = 0; w < CHUNK_T / 64; ++w) {
        unsigned long long bits = mask[(t0 >> 6) + w];
        while (bits) {
            int bit = __builtin_ctzll(bits);
            bits &= bits - 1;
            const float4* sb = sa + (size_t)(t0 + w*64 + bit) * SLOW_F4;
            float4 S0 = sb[0], S1 = sb[1], S2 = sb[2], S3 = sb[3], S4 = sb[4];
            m.x = fminf(m.x, tri_d2(PXs, PYs, PZs, S0, S1, S2, S3, S4));
        }
    }

    float r = fminf(m.x, m.y);
    atomicMin(&minD[p], __float_as_uint(fmaxf(r, 0.0f)));
}

// ---------------------------------------------------------------------------
// Kernel 3a: partial reductions, 8 blocks per batch.
// ---------------------------------------------------------------------------
__global__ __launch_bounds__(256) void reduce1_kernel(
    const unsigned int* __restrict__ minD, const float* __restrict__ verts,
    float* __restrict__ sums, unsigned int* __restrict__ ykmin,
    unsigned int* __restrict__ ykmax)
{
    int blk = blockIdx.x;          // 0 .. 15
    int b = blk >> 3, part = blk & 7;
    int tid = threadIdx.x;

    float s = 0.0f;
    int i0 = part * (PP / 8), i1 = i0 + (PP / 8);
    for (int i = i0 + tid; i < i1; i += 256)
        s += __uint_as_float(minD[b * PP + i]);

    float ymin = 3.4e38f, ymax = -3.4e38f;
    int v0 = part * 513, v1 = min(v0 + 513, VV);
    for (int i = v0 + tid; i < v1; i += 256) {
        float y = verts[((size_t)b * VV + i) * 3 + 1];
        ymin = fminf(ymin, y); ymax = fmaxf(ymax, y);
    }

    for (int off = 32; off > 0; off >>= 1) {
        s += __shfl_down(s, off);
        ymin = fminf(ymin, __shfl_down(ymin, off));
        ymax = fmaxf(ymax, __shfl_down(ymax, off));
    }

    __shared__ float shs[4], shmn[4], shmx[4];
    if ((tid & 63) == 0) {
        int w = tid >> 6;
        shs[w] = s; shmn[w] = ymin; shmx[w] = ymax;
    }
    __syncthreads();
    if (tid == 0) {
        float tot = shs[0], mn = shmn[0], mx = shmx[0];
        for (int w = 1; w < 4; ++w) {
            tot += shs[w];
            mn = fminf(mn, shmn[w]);
            mx = fmaxf(mx, shmx[w]);
        }
        atomicAdd(&sums[b], tot);
        atomicMin(&ykmin[b], fkey(mn));
        atomicMax(&ykmax[b], fkey(mx));
    }
}

// ---------------------------------------------------------------------------
// Kernel 3b: finish — combine per-batch partials into the scalar loss.
// ---------------------------------------------------------------------------
__global__ __launch_bounds__(64) void reduce2_kernel(
    const float* __restrict__ sums, const unsigned int* __restrict__ ykmin,
    const unsigned int* __restrict__ ykmax, float* __restrict__ out)
{
    if (threadIdx.x == 0) {
        float r = 0.0f;
        for (int b = 0; b < BB; ++b) {
            float h = funkey(ykmax[b]) - funkey(ykmin[b]);
            r += sqrtf(sums[b]) / h;
        }
        out[0] = r * 0.5f;   // mean over B=2, LOSS_WEIGHT=1
    }
}

// ---------------------------------------------------------------------------
extern "C" void kernel_launch(void* const* d_in, const int* in_sizes, int n_in,
                              void* d_out, int out_size, void* d_ws, size_t ws_size,
                              hipStream_t stream) {
    const float* pts   = (const float*)d_in[0];   // [B,P,3]
    const float* verts = (const float*)d_in[1];   // [B,V,3]
    const int*   faces = (const int*)d_in[2];     // [B,F,3]
    float* out = (float*)d_out;

    char* w = (char*)d_ws;
    float* scr = (float*)w;                                         // 384 KB
    w += (size_t)(BB * FF / 2) * SCR_ST * sizeof(float);
    float* rest = (float*)w;                                        // 1.25 MB
    w += (size_t)(BB * FF / 2) * RST_ST * sizeof(float);
    float4* slowrec = (float4*)w;                                   // 1.25 MB
    w += (size_t)BB * FF * SLOW_F4 * sizeof(float4);
    unsigned long long* mask = (unsigned long long*)w;              // 2 KB
    w += (size_t)(BB * FF / 64) * sizeof(unsigned long long);
    unsigned int* minD = (unsigned int*)w;                          // 64 KB
    w += (size_t)BB * PP * sizeof(unsigned int);
    float* sums = (float*)w;          w += BB * sizeof(float);
    unsigned int* ykmin = (unsigned int*)w; w += BB * sizeof(unsigned int);
    unsigned int* ykmax = (unsigned int*)w;

    precompute_kernel<<<(BB * FF + 255) / 256, 256, 0, stream>>>(
        verts, faces, scr, rest, slowrec, mask, minD, sums, ykmin, ykmax);

    dim3 grid(BB * PP / PTS_PER_BLOCK, NSLICES);
    dist_kernel<<<grid, 256, 0, stream>>>(
        pts, (const f2*)scr, (const f2*)rest, slowrec, mask, minD);

    reduce1_kernel<<<16, 256, 0, stream>>>(minD, verts, sums, ykmin, ykmax);
    reduce2_kernel<<<1, 64, 0, stream>>>(sums, ykmin, ykmax, out);
}

// Round 10
// 220.764 us; speedup vs baseline: 1.2042x; 1.2042x over previous
//
#include <hip/hip_runtime.h>

#define EPSF 1e-12f
constexpr int BB = 2;
constexpr int PP = 8192;
constexpr int VV = 4098;
constexpr int FF = 8192;

constexpr int SLOW_F4 = 5;            // verbatim record: 5 x float4
constexpr int NCONST = 22;            // fast consts per triangle
constexpr int PTS_PER_BLOCK = 2048;   // 8 points/thread x 256 threads
constexpr int NSLICES = 128;
constexpr int CHUNK_T = FF / NSLICES; // 64 tris/block = 1 mask word

typedef float f2 __attribute__((ext_vector_type(2)));

__device__ __forceinline__ f2 vfma(f2 a, f2 b, f2 c) {
#if __has_builtin(__builtin_elementwise_fma)
    return __builtin_elementwise_fma(a, b, c);
#else
    return (f2){fmaf(a.x, b.x, c.x), fmaf(a.y, b.y, c.y)};
#endif
}
__device__ __forceinline__ f2 vmin2(f2 a, f2 b) { return __builtin_elementwise_min(a, b); }
__device__ __forceinline__ f2 vmax2(f2 a, f2 b) { return __builtin_elementwise_max(a, b); }
__device__ __forceinline__ f2 bc(float s) { return (f2){s, s}; }
__device__ __forceinline__ f2 clamp01(f2 x) { return vmin2(vmax2(x, bc(0.0f)), bc(1.0f)); }

// ---------------------------------------------------------------------------
// Kernel 1: pair-interleaved fast records + slow records + sliver mask + inits.
// Fast consts per tri (c): 0-2 ab, 3 ka1, 4-6 ac, 7 ka2, 8-10 a, 11 aa*,
// 12 ab2, 13 ac2, 14 abac, 15 bc2, 16 kbc=ab2-abac, 17 iab2, 18 iac2,
// 19 ibc2, 20 inn, 21 nn.
// Stored interleaved per tri-PAIR: pr[(idx>>1)*44 + 2*c + (idx&1)] so the
// dist kernel loads each constant as an f2=(tri_even,tri_odd) pair.
// Sliver poisoning: aa*=+inf => ap2/bp2/dAB/dAC/dBC/dIN all +inf (no 0*inf).
// ---------------------------------------------------------------------------
__global__ __launch_bounds__(256) void precompute_kernel(
    const float* __restrict__ verts, const int* __restrict__ faces,
    float* __restrict__ pairrec, float4* __restrict__ slowrec,
    unsigned long long* __restrict__ mask, unsigned int* __restrict__ minD,
    unsigned int* __restrict__ done)
{
    int idx = blockIdx.x * 256 + threadIdx.x;   // grid exactly covers BB*FF
    if (idx == 0) *done = 0u;
    if (idx < BB * PP) minD[idx] = 0x7F800000u; // +inf
    if (idx >= BB * FF) return;

    int b = idx / FF;
    const float* vb = verts + (size_t)b * VV * 3;
    int i0 = faces[idx * 3 + 0];
    int i1 = faces[idx * 3 + 1];
    int i2 = faces[idx * 3 + 2];

    float ax = vb[i0*3+0], ay = vb[i0*3+1], az = vb[i0*3+2];
    float bx = vb[i1*3+0], by = vb[i1*3+1], bz = vb[i1*3+2];
    float cx = vb[i2*3+0], cy = vb[i2*3+1], cz = vb[i2*3+2];

    // plain fp32 subs: bit-match numpy (shared by both records)
    float abx = bx-ax, aby = by-ay, abz = bz-az;
    float acx = cx-ax, acy = cy-ay, acz = cz-az;
    float bcx = cx-bx, bcy = cy-by, bcz = cz-bz;

    {   // slow record (read only for flagged tris)
        float4* t = slowrec + (size_t)idx * SLOW_F4;
        t[0] = make_float4(ax, ay, az, abx);
        t[1] = make_float4(bx, by, bz, aby);
        t[2] = make_float4(cx, cy, cz, abz);
        t[3] = make_float4(acx, acy, acz, bcx);
        t[4] = make_float4(bcy, bcz, 0.0f, 0.0f);
    }

    float nx = aby*acz - abz*acy;
    float ny = abz*acx - abx*acz;
    float nz = abx*acy - aby*acx;

    float ka1  = abx*ax + aby*ay + abz*az;
    float ka2  = acx*ax + acy*ay + acz*az;
    float aa   = ax*ax + ay*ay + az*az;
    float abac = abx*acx + aby*acy + abz*acz;

    float ab2 = abx*abx + aby*aby + abz*abz;
    float ac2 = acx*acx + acy*acy + acz*acz;
    float bc2 = bcx*bcx + bcy*bcy + bcz*bcz;
    float nn  = nx*nx + ny*ny + nz*nz;

    float inv_ab2 = 1.0f / fmaxf(ab2, EPSF);
    float inv_ac2 = 1.0f / fmaxf(ac2, EPSF);
    float inv_bc2 = 1.0f / fmaxf(bc2, EPSF);
    float inv_nn  = 1.0f / fmaxf(nn,  EPSF);

    // sliver/degenerate classifier: sin^2(angle at a) <= 3e-2 or tiny edges
    bool slowtri = !((nn > 0.03f * (ab2 * ac2)) &&
                     (ab2 > 1e-4f) && (ac2 > 1e-4f) && (bc2 > 1e-4f));

    unsigned long long mb = __ballot(slowtri);
    if ((threadIdx.x & 63) == 0) mask[idx >> 6] = mb;

    float INF = __uint_as_float(0x7F800000u);
    float cvals[NCONST] = {
        abx, aby, abz, ka1,
        acx, acy, acz, ka2,
        ax,  ay,  az,  slowtri ? INF : aa,
        ab2, ac2, abac, bc2,
        ab2 - abac, inv_ab2, inv_ac2, inv_bc2,
        inv_nn, nn
    };
    float* pr = pairrec + (size_t)(idx >> 1) * (2 * NCONST) + (idx & 1);
#pragma unroll
    for (int c = 0; c < NCONST; ++c) pr[2*c] = cvals[c];
}

// ---------------------------------------------------------------------------
// Verbatim fp32 port (bit-exact vs numpy) — slivers only. Proven in R3.
// ---------------------------------------------------------------------------
__device__ __forceinline__ float tri_d2(
    float px, float py, float pz,
    float4 R0, float4 R1, float4 R2, float4 R3, float4 R4)
{
#pragma clang fp contract(off)
    float ax = R0.x, ay = R0.y, az = R0.z;
    float bx = R1.x, by = R1.y, bz = R1.z;
    float cx = R2.x, cy = R2.y, cz = R2.z;
    float abx = R0.w, aby = R1.w, abz = R2.w;
    float acx = R3.x, acy = R3.y, acz = R3.z;
    float bcx = R3.w, bcy = R4.x, bcz = R4.y;

    float apx = px - ax, apy = py - ay, apz = pz - az;
    float d1 = (abx*apx + aby*apy) + abz*apz;
    float d2 = (acx*apx + acy*apy) + acz*apz;
    float bpx = px - bx, bpy = py - by, bpz = pz - bz;
    float d3 = (abx*bpx + aby*bpy) + abz*bpz;
    float d4 = (acx*bpx + acy*bpy) + acz*bpz;
    float cqx = px - cx, cqy = py - cy, cqz = pz - cz;
    float d5 = (abx*cqx + aby*cqy) + abz*cqz;
    float d6 = (acx*cqx + acy*cqy) + acz*cqz;

    float va = d3*d6 - d5*d4;
    float vb = d5*d2 - d1*d6;
    float vc = d1*d4 - d3*d2;
    float u43 = d4 - d3;
    float u56 = d5 - d6;

    bool c1 = (d1 <= 0.0f) && (d2 <= 0.0f);
    bool c2 = (d3 >= 0.0f) && (d4 <= d3);
    bool c3 = (d6 >= 0.0f) && (d5 <= d6);
    bool c4 = (vc <= 0.0f) && (d1 >= 0.0f) && (d3 <= 0.0f);
    bool c5 = (vb <= 0.0f) && (d2 >= 0.0f) && (d6 <= 0.0f);
    bool c6 = (va <= 0.0f) && (u43 >= 0.0f) && (u56 >= 0.0f);

    int reg = c1 ? 0 : (c2 ? 1 : (c3 ? 2 : (c4 ? 3 : (c5 ? 4 : (c6 ? 5 : 6)))));

    float denom = fmaxf((va + vb) + vc, EPSF);
    float den1 = (reg == 3) ? fmaxf(d1 - d3, EPSF)
               : (reg == 5) ? fmaxf(u43 + u56, EPSF)
               : (reg == 6) ? denom : 1.0f;
    float num1 = (reg == 3) ? d1
               : (reg == 5) ? u43
               : (reg == 6) ? vb : 0.0f;
    float den2 = (reg == 4) ? fmaxf(d2 - d6, EPSF)
               : (reg == 6) ? denom : 1.0f;
    float num2 = (reg == 4) ? d2
               : (reg == 6) ? vc : 0.0f;
    float s = num1 / den1;
    float t = num2 / den2;

    bool useB = (reg == 1) || (reg == 5);
    bool useC = (reg == 2);
    float basex = useB ? bx : (useC ? cx : ax);
    float basey = useB ? by : (useC ? cy : ay);
    float basez = useB ? bz : (useC ? cz : az);
    bool e1bc = (reg == 5);
    float e1x = e1bc ? bcx : abx;
    float e1y = e1bc ? bcy : aby;
    float e1z = e1bc ? bcz : abz;

    float cpx = (basex + e1x*s) + acx*t;
    float cpy = (basey + e1y*s) + acy*t;
    float cpz = (basez + e1z*s) + acz*t;
    float rx = px - cpx, ry = py - cpy, rz = pz - cpz;
    return (rx*rx + ry*ry) + rz*rz;
}

// ---------------------------------------------------------------------------
// Kernel 2: 8 points/thread, two triangles per packed op, 64 tris/block.
// Trimmed formulation: no n-dot; dIN from barycentrics; inside test via
// min3(v, w, nn-(v+w)) >= 0. Fused final reduction via last-block ticket.
// ---------------------------------------------------------------------------
__global__ __launch_bounds__(256, 4) void dist_kernel(
    const float* __restrict__ pts, const f2* __restrict__ pair,
    const float4* __restrict__ sa, const unsigned long long* __restrict__ mask,
    const float* __restrict__ verts, unsigned int* __restrict__ minD,
    unsigned int* __restrict__ done, float* __restrict__ out)
{
    const float INF = __uint_as_float(0x7F800000u);
    int tid   = threadIdx.x;
    int pg    = blockIdx.x;        // 0 .. 7
    int slice = blockIdx.y;        // 0 .. 127

    int b  = pg >> 2;              // 4 point-groups per batch
    int p0 = pg * PTS_PER_BLOCK + tid;

    f2 X[8], Y[8], Z[8], W[8], m[8];
#pragma unroll
    for (int k = 0; k < 8; ++k) {
        int p = p0 + k * 256;
        X[k] = bc(pts[p*3+0]); Y[k] = bc(pts[p*3+1]); Z[k] = bc(pts[p*3+2]);
        W[k] = vfma(X[k], X[k], vfma(Y[k], Y[k], Z[k] * Z[k]));
        m[k] = bc(INF);
    }

    int t0 = b * FF + slice * CHUNK_T;
    const f2* cb = pair + (size_t)(t0 >> 1) * NCONST;

    for (int tp = 0; tp < CHUNK_T / 2; ++tp) {
        const f2* c = cb + tp * NCONST;
        f2 abx=c[0], aby=c[1], abz=c[2], ka1=c[3];
        f2 acx=c[4], acy=c[5], acz=c[6], ka2=c[7];
        f2 ax=c[8],  ay=c[9],  az=c[10], aa=c[11];
        f2 ab2=c[12], ac2=c[13], abac=c[14], bc2=c[15];
        f2 kbc=c[16], iab2=c[17], iac2=c[18], ibc2=c[19];
        f2 inn=c[20], nn=c[21];

#pragma unroll
        for (int k = 0; k < 8; ++k) {
            f2 sab = vfma(abx, X[k], vfma(aby, Y[k], abz * Z[k]));
            f2 sac = vfma(acx, X[k], vfma(acy, Y[k], acz * Z[k]));
            f2 adp = vfma(ax,  X[k], vfma(ay,  Y[k], az  * Z[k]));

            f2 d1 = sab - ka1, d2 = sac - ka2;
            f2 ap2 = vfma(bc(-2.0f), adp, W[k]) + aa;   // +inf if poisoned
            f2 bp2 = vfma(bc(-2.0f), d1, ap2) + ab2;

            f2 sA = clamp01(d1 * iab2);
            f2 dAB = vfma(-sA, vfma(-sA, ab2, d1 + d1), ap2);
            f2 sC = clamp01(d2 * iac2);
            f2 dAC = vfma(-sC, vfma(-sC, ac2, d2 + d2), ap2);
            f2 u43 = (d2 - d1) + kbc;
            f2 sB = clamp01(u43 * ibc2);
            f2 dBC = vfma(-sB, vfma(-sB, bc2, u43 + u43), bp2);

            f2 v = vfma(ac2, d1, -(abac * d2));      // == reference vb
            f2 w = vfma(ab2, d2, -(abac * d1));      // == reference vc
            f2 s = v + w;
            f2 dprod = vfma(w, d2, v * d1);
            f2 dIN = vfma(-dprod, inn, ap2);         // ap2 - |inplane|^2
            f2 g = vmin2(vmin2(v, w), nn - s);       // inside iff g >= 0
            f2 dI = vfma(vmin2(g, bc(0.0f)), bc(-1e30f), dIN);

            m[k] = vmin2(m[k], vmin2(vmin2(dAB, dAC), vmin2(dBC, dI)));
        }
    }

    // Phase B: bit-exact eval for flagged slivers (one mask word per block)
    unsigned long long bits = mask[t0 >> 6];
    while (bits) {
        int bit = __builtin_ctzll(bits);
        bits &= bits - 1;
        const float4* sb = sa + (size_t)(t0 + bit) * SLOW_F4;
        float4 S0 = sb[0], S1 = sb[1], S2 = sb[2], S3 = sb[3], S4 = sb[4];
#pragma unroll
        for (int k = 0; k < 8; ++k)
            m[k].x = fminf(m[k].x, tri_d2(X[k].x, Y[k].x, Z[k].x, S0, S1, S2, S3, S4));
    }

    // fold halves, clamp (monotone), float-as-uint atomicMin (values >= 0)
#pragma unroll
    for (int k = 0; k < 8; ++k) {
        float r = fminf(m[k].x, m[k].y);
        atomicMin(&minD[p0 + k*256], __float_as_uint(fmaxf(r, 0.0f)));
    }

    // -------- fused final reduction: last block to finish does it --------
    __shared__ int isLast;
    __threadfence();                        // order our atomicMins before ticket
    if (tid == 0) {
        unsigned int t = atomicAdd(done, 1u);
        isLast = (t == (unsigned int)(gridDim.x * gridDim.y) - 1u);
    }
    __syncthreads();
    if (!isLast) return;

    float s0 = 0.0f, s1 = 0.0f;
    for (int i = tid; i < PP; i += 256) {
        // atomicAdd(p,0) = device-coherent read (plain loads may hit stale L1/L2)
        s0 += __uint_as_float(atomicAdd(&minD[i], 0u));
        s1 += __uint_as_float(atomicAdd(&minD[PP + i], 0u));
    }
    float mn0 = 3.4e38f, mx0 = -3.4e38f, mn1 = 3.4e38f, mx1 = -3.4e38f;
    for (int i = tid; i < VV; i += 256) {
        float y0 = verts[(size_t)i * 3 + 1];
        float y1 = verts[((size_t)VV + i) * 3 + 1];
        mn0 = fminf(mn0, y0); mx0 = fmaxf(mx0, y0);
        mn1 = fminf(mn1, y1); mx1 = fmaxf(mx1, y1);
    }
    for (int off = 32; off > 0; off >>= 1) {
        s0 += __shfl_down(s0, off);  s1 += __shfl_down(s1, off);
        mn0 = fminf(mn0, __shfl_down(mn0, off));
        mx0 = fmaxf(mx0, __shfl_down(mx0, off));
        mn1 = fminf(mn1, __shfl_down(mn1, off));
        mx1 = fmaxf(mx1, __shfl_down(mx1, off));
    }
    __shared__ float sh[6][4];
    if ((tid & 63) == 0) {
        int w = tid >> 6;
        sh[0][w] = s0; sh[1][w] = s1;
        sh[2][w] = mn0; sh[3][w] = mx0;
        sh[4][w] = mn1; sh[5][w] = mx1;
    }
    __syncthreads();
    if (tid == 0) {
        float t0s = sh[0][0], t1s = sh[1][0];
        float a0 = sh[2][0], b0 = sh[3][0], a1 = sh[4][0], b1 = sh[5][0];
        for (int w = 1; w < 4; ++w) {
            t0s += sh[0][w]; t1s += sh[1][w];
            a0 = fminf(a0, sh[2][w]); b0 = fmaxf(b0, sh[3][w]);
            a1 = fminf(a1, sh[4][w]); b1 = fmaxf(b1, sh[5][w]);
        }
        out[0] = 0.5f * (sqrtf(t0s) / (b0 - a0) + sqrtf(t1s) / (b1 - a1));
    }
}

// ---------------------------------------------------------------------------
extern "C" void kernel_launch(void* const* d_in, const int* in_sizes, int n_in,
                              void* d_out, int out_size, void* d_ws, size_t ws_size,
                              hipStream_t stream) {
    const float* pts   = (const float*)d_in[0];   // [B,P,3]
    const float* verts = (const float*)d_in[1];   // [B,V,3]
    const int*   faces = (const int*)d_in[2];     // [B,F,3]
    float* out = (float*)d_out;

    char* w = (char*)d_ws;
    float* pairrec = (float*)w;                                     // 2.75 MB
    w += (size_t)(BB * FF / 2) * (2 * NCONST) * sizeof(float);
    float4* slowrec = (float4*)w;                                   // 1.25 MB
    w += (size_t)BB * FF * SLOW_F4 * sizeof(float4);
    unsigned long long* mask = (unsigned long long*)w;              // 2 KB
    w += (size_t)(BB * FF / 64) * sizeof(unsigned long long);
    unsigned int* minD = (unsigned int*)w;                          // 64 KB
    w += (size_t)BB * PP * sizeof(unsigned int);
    unsigned int* done = (unsigned int*)w;                          // 4 B

    precompute_kernel<<<(BB * FF + 255) / 256, 256, 0, stream>>>(
        verts, faces, pairrec, slowrec, mask, minD, done);

    dim3 grid(BB * PP / PTS_PER_BLOCK, NSLICES);   // 8 x 128 = 1024 blocks
    dist_kernel<<<grid, 256, 0, stream>>>(
        pts, (const f2*)pairrec, slowrec, mask, verts, minD, done, out);
}

// Round 11
// 199.360 us; speedup vs baseline: 1.3335x; 1.1074x over previous
//
#include <hip/hip_runtime.h>

#define EPSF 1e-12f
constexpr int BB = 2;
constexpr int PP = 8192;
constexpr int VV = 4098;
constexpr int FF = 8192;

constexpr int SLOW_F4 = 5;            // verbatim record: 5 x float4
constexpr int NCONST = 22;            // fast consts per triangle
constexpr int PTS_PER_BLOCK = 1024;   // 4 points/thread x 256 threads
constexpr int NSLICES = 128;
constexpr int CHUNK_T = FF / NSLICES; // 64 tris/block = 1 mask word

typedef float f2 __attribute__((ext_vector_type(2)));

__device__ __forceinline__ f2 vfma(f2 a, f2 b, f2 c) {
#if __has_builtin(__builtin_elementwise_fma)
    return __builtin_elementwise_fma(a, b, c);
#else
    return (f2){fmaf(a.x, b.x, c.x), fmaf(a.y, b.y, c.y)};
#endif
}
__device__ __forceinline__ f2 vmin2(f2 a, f2 b) { return __builtin_elementwise_min(a, b); }
__device__ __forceinline__ f2 vmax2(f2 a, f2 b) { return __builtin_elementwise_max(a, b); }
__device__ __forceinline__ f2 bc(float s) { return (f2){s, s}; }
__device__ __forceinline__ f2 clamp01(f2 x) { return vmin2(vmax2(x, bc(0.0f)), bc(1.0f)); }

// monotone float<->uint for atomicMin/Max on y-extent
__device__ __forceinline__ unsigned int fkey(float f) {
    unsigned int u = __float_as_uint(f);
    return (u >> 31) ? ~u : (u | 0x80000000u);
}
__device__ __forceinline__ float funkey(unsigned int k) {
    unsigned int u = (k >> 31) ? (k ^ 0x80000000u) : ~k;
    return __uint_as_float(u);
}

// ---------------------------------------------------------------------------
// Kernel 1: pair-interleaved fast records + slow records + sliver mask + inits.
// Fast consts per tri (c): 0-2 ab, 3 ka1, 4-6 ac, 7 ka2, 8-10 a, 11 aa*,
// 12 ab2, 13 ac2, 14 abac, 15 bc2, 16 kbc=ab2-abac, 17 iab2, 18 iac2,
// 19 ibc2, 20 inn, 21 nn.
// Stored interleaved per tri-PAIR: pr[(idx>>1)*44 + 2*c + (idx&1)] so the
// dist kernel loads each constant as an f2=(tri_even,tri_odd) pair
// (wave-uniform -> SGPR pair, direct v_pk_* operand).
// Sliver poisoning: aa*=+inf => ap2/bp2/dAB/dAC/dBC/dIN all +inf (no 0*inf).
// ---------------------------------------------------------------------------
__global__ __launch_bounds__(256) void precompute_kernel(
    const float* __restrict__ verts, const int* __restrict__ faces,
    float* __restrict__ pairrec, float4* __restrict__ slowrec,
    unsigned long long* __restrict__ mask, unsigned int* __restrict__ minD,
    float* __restrict__ sums, unsigned int* __restrict__ ykmin,
    unsigned int* __restrict__ ykmax)
{
    int idx = blockIdx.x * 256 + threadIdx.x;   // grid exactly covers BB*FF
    if (idx < BB) { sums[idx] = 0.0f; ykmin[idx] = 0xFFFFFFFFu; ykmax[idx] = 0u; }
    if (idx < BB * PP) minD[idx] = 0x7F800000u; // +inf
    if (idx >= BB * FF) return;

    int b = idx / FF;
    const float* vb = verts + (size_t)b * VV * 3;
    int i0 = faces[idx * 3 + 0];
    int i1 = faces[idx * 3 + 1];
    int i2 = faces[idx * 3 + 2];

    float ax = vb[i0*3+0], ay = vb[i0*3+1], az = vb[i0*3+2];
    float bx = vb[i1*3+0], by = vb[i1*3+1], bz = vb[i1*3+2];
    float cx = vb[i2*3+0], cy = vb[i2*3+1], cz = vb[i2*3+2];

    // plain fp32 subs: bit-match numpy (shared by both records)
    float abx = bx-ax, aby = by-ay, abz = bz-az;
    float acx = cx-ax, acy = cy-ay, acz = cz-az;
    float bcx = cx-bx, bcy = cy-by, bcz = cz-bz;

    {   // slow record (read only for flagged tris)
        float4* t = slowrec + (size_t)idx * SLOW_F4;
        t[0] = make_float4(ax, ay, az, abx);
        t[1] = make_float4(bx, by, bz, aby);
        t[2] = make_float4(cx, cy, cz, abz);
        t[3] = make_float4(acx, acy, acz, bcx);
        t[4] = make_float4(bcy, bcz, 0.0f, 0.0f);
    }

    float nx = aby*acz - abz*acy;
    float ny = abz*acx - abx*acz;
    float nz = abx*acy - aby*acx;

    float ka1  = abx*ax + aby*ay + abz*az;
    float ka2  = acx*ax + acy*ay + acz*az;
    float aa   = ax*ax + ay*ay + az*az;
    float abac = abx*acx + aby*acy + abz*acz;

    float ab2 = abx*abx + aby*aby + abz*abz;
    float ac2 = acx*acx + acy*acy + acz*acz;
    float bc2 = bcx*bcx + bcy*bcy + bcz*bcz;
    float nn  = nx*nx + ny*ny + nz*nz;

    float inv_ab2 = 1.0f / fmaxf(ab2, EPSF);
    float inv_ac2 = 1.0f / fmaxf(ac2, EPSF);
    float inv_bc2 = 1.0f / fmaxf(bc2, EPSF);
    float inv_nn  = 1.0f / fmaxf(nn,  EPSF);

    // sliver/degenerate classifier: sin^2(angle at a) <= 3e-2 or tiny edges
    bool slowtri = !((nn > 0.03f * (ab2 * ac2)) &&
                     (ab2 > 1e-4f) && (ac2 > 1e-4f) && (bc2 > 1e-4f));

    unsigned long long mb = __ballot(slowtri);
    if ((threadIdx.x & 63) == 0) mask[idx >> 6] = mb;

    float INF = __uint_as_float(0x7F800000u);
    float cvals[NCONST] = {
        abx, aby, abz, ka1,
        acx, acy, acz, ka2,
        ax,  ay,  az,  slowtri ? INF : aa,
        ab2, ac2, abac, bc2,
        ab2 - abac, inv_ab2, inv_ac2, inv_bc2,
        inv_nn, nn
    };
    float* pr = pairrec + (size_t)(idx >> 1) * (2 * NCONST) + (idx & 1);
#pragma unroll
    for (int c = 0; c < NCONST; ++c) pr[2*c] = cvals[c];
}

// ---------------------------------------------------------------------------
// Verbatim fp32 port (bit-exact vs numpy) — slivers only. Proven in R3.
// ---------------------------------------------------------------------------
__device__ __forceinline__ float tri_d2(
    float px, float py, float pz,
    float4 R0, float4 R1, float4 R2, float4 R3, float4 R4)
{
#pragma clang fp contract(off)
    float ax = R0.x, ay = R0.y, az = R0.z;
    float bx = R1.x, by = R1.y, bz = R1.z;
    float cx = R2.x, cy = R2.y, cz = R2.z;
    float abx = R0.w, aby = R1.w, abz = R2.w;
    float acx = R3.x, acy = R3.y, acz = R3.z;
    float bcx = R3.w, bcy = R4.x, bcz = R4.y;

    float apx = px - ax, apy = py - ay, apz = pz - az;
    float d1 = (abx*apx + aby*apy) + abz*apz;
    float d2 = (acx*apx + acy*apy) + acz*apz;
    float bpx = px - bx, bpy = py - by, bpz = pz - bz;
    float d3 = (abx*bpx + aby*bpy) + abz*bpz;
    float d4 = (acx*bpx + acy*bpy) + acz*bpz;
    float cqx = px - cx, cqy = py - cy, cqz = pz - cz;
    float d5 = (abx*cqx + aby*cqy) + abz*cqz;
    float d6 = (acx*cqx + acy*cqy) + acz*cqz;

    float va = d3*d6 - d5*d4;
    float vb = d5*d2 - d1*d6;
    float vc = d1*d4 - d3*d2;
    float u43 = d4 - d3;
    float u56 = d5 - d6;

    bool c1 = (d1 <= 0.0f) && (d2 <= 0.0f);
    bool c2 = (d3 >= 0.0f) && (d4 <= d3);
    bool c3 = (d6 >= 0.0f) && (d5 <= d6);
    bool c4 = (vc <= 0.0f) && (d1 >= 0.0f) && (d3 <= 0.0f);
    bool c5 = (vb <= 0.0f) && (d2 >= 0.0f) && (d6 <= 0.0f);
    bool c6 = (va <= 0.0f) && (u43 >= 0.0f) && (u56 >= 0.0f);

    int reg = c1 ? 0 : (c2 ? 1 : (c3 ? 2 : (c4 ? 3 : (c5 ? 4 : (c6 ? 5 : 6)))));

    float denom = fmaxf((va + vb) + vc, EPSF);
    float den1 = (reg == 3) ? fmaxf(d1 - d3, EPSF)
               : (reg == 5) ? fmaxf(u43 + u56, EPSF)
               : (reg == 6) ? denom : 1.0f;
    float num1 = (reg == 3) ? d1
               : (reg == 5) ? u43
               : (reg == 6) ? vb : 0.0f;
    float den2 = (reg == 4) ? fmaxf(d2 - d6, EPSF)
               : (reg == 6) ? denom : 1.0f;
    float num2 = (reg == 4) ? d2
               : (reg == 6) ? vc : 0.0f;
    float s = num1 / den1;
    float t = num2 / den2;

    bool useB = (reg == 1) || (reg == 5);
    bool useC = (reg == 2);
    float basex = useB ? bx : (useC ? cx : ax);
    float basey = useB ? by : (useC ? cy : ay);
    float basez = useB ? bz : (useC ? cz : az);
    bool e1bc = (reg == 5);
    float e1x = e1bc ? bcx : abx;
    float e1y = e1bc ? bcy : aby;
    float e1z = e1bc ? bcz : abz;

    float cpx = (basex + e1x*s) + acx*t;
    float cpy = (basey + e1y*s) + acy*t;
    float cpz = (basez + e1z*s) + acz*t;
    float rx = px - cpx, ry = py - cpy, rz = pz - cpz;
    return (rx*rx + ry*ry) + rz*rz;
}

// ---------------------------------------------------------------------------
// Kernel 2: 4 points/thread, two triangles per packed op, 64 tris/block.
// Trimmed formulation (validated absmax 0.0 in R10): no n-dot; dIN from
// barycentrics v,w; inside test min3(v, w, nn-(v+w)) >= 0; branchless gate.
// ---------------------------------------------------------------------------
__global__ __launch_bounds__(256) void dist_kernel(
    const float* __restrict__ pts, const f2* __restrict__ pair,
    const float4* __restrict__ sa, const unsigned long long* __restrict__ mask,
    unsigned int* __restrict__ minD)
{
    const float INF = __uint_as_float(0x7F800000u);
    int tid   = threadIdx.x;
    int pg    = blockIdx.x;        // 0 .. 15
    int slice = blockIdx.y;        // 0 .. 127

    int b  = pg >> 3;              // 8 point-groups per batch
    int p0 = pg * PTS_PER_BLOCK + tid;

    f2 X[4], Y[4], Z[4], W[4], m[4];
#pragma unroll
    for (int k = 0; k < 4; ++k) {
        int p = p0 + k * 256;
        X[k] = bc(pts[p*3+0]); Y[k] = bc(pts[p*3+1]); Z[k] = bc(pts[p*3+2]);
        W[k] = vfma(X[k], X[k], vfma(Y[k], Y[k], Z[k] * Z[k]));
        m[k] = bc(INF);
    }

    int t0 = b * FF + slice * CHUNK_T;
    const f2* cb = pair + (size_t)(t0 >> 1) * NCONST;

    for (int tp = 0; tp < CHUNK_T / 2; ++tp) {
        const f2* c = cb + tp * NCONST;
        f2 abx=c[0], aby=c[1], abz=c[2], ka1=c[3];
        f2 acx=c[4], acy=c[5], acz=c[6], ka2=c[7];
        f2 ax=c[8],  ay=c[9],  az=c[10], aa=c[11];
        f2 ab2=c[12], ac2=c[13], abac=c[14], bc2=c[15];
        f2 kbc=c[16], iab2=c[17], iac2=c[18], ibc2=c[19];
        f2 inn=c[20], nn=c[21];

#pragma unroll
        for (int k = 0; k < 4; ++k) {
            f2 sab = vfma(abx, X[k], vfma(aby, Y[k], abz * Z[k]));
            f2 sac = vfma(acx, X[k], vfma(acy, Y[k], acz * Z[k]));
            f2 adp = vfma(ax,  X[k], vfma(ay,  Y[k], az  * Z[k]));

            f2 d1 = sab - ka1, d2 = sac - ka2;
            f2 ap2 = vfma(bc(-2.0f), adp, W[k]) + aa;   // +inf if poisoned
            f2 bp2 = vfma(bc(-2.0f), d1, ap2) + ab2;

            f2 sA = clamp01(d1 * iab2);
            f2 dAB = vfma(-sA, vfma(-sA, ab2, d1 + d1), ap2);
            f2 sC = clamp01(d2 * iac2);
            f2 dAC = vfma(-sC, vfma(-sC, ac2, d2 + d2), ap2);
            f2 u43 = (d2 - d1) + kbc;
            f2 sB = clamp01(u43 * ibc2);
            f2 dBC = vfma(-sB, vfma(-sB, bc2, u43 + u43), bp2);

            f2 v = vfma(ac2, d1, -(abac * d2));      // == reference vb
            f2 w = vfma(ab2, d2, -(abac * d1));      // == reference vc
            f2 s = v + w;
            f2 dprod = vfma(w, d2, v * d1);
            f2 dIN = vfma(-dprod, inn, ap2);         // ap2 - |inplane|^2
            f2 g = vmin2(vmin2(v, w), nn - s);       // inside iff g >= 0
            f2 dI = vfma(vmin2(g, bc(0.0f)), bc(-1e30f), dIN);

            m[k] = vmin2(m[k], vmin2(vmin2(dAB, dAC), vmin2(dBC, dI)));
        }
    }

    // Phase B: bit-exact eval for flagged slivers (one mask word per block)
    unsigned long long bits = mask[t0 >> 6];
    while (bits) {
        int bit = __builtin_ctzll(bits);
        bits &= bits - 1;
        const float4* sb = sa + (size_t)(t0 + bit) * SLOW_F4;
        float4 S0 = sb[0], S1 = sb[1], S2 = sb[2], S3 = sb[3], S4 = sb[4];
#pragma unroll
        for (int k = 0; k < 4; ++k)
            m[k].x = fminf(m[k].x, tri_d2(X[k].x, Y[k].x, Z[k].x, S0, S1, S2, S3, S4));
    }

    // fold halves, clamp (monotone), float-as-uint atomicMin (values >= 0)
#pragma unroll
    for (int k = 0; k < 4; ++k) {
        float r = fminf(m[k].x, m[k].y);
        atomicMin(&minD[p0 + k*256], __float_as_uint(fmaxf(r, 0.0f)));
    }
}

// ---------------------------------------------------------------------------
// Kernel 3a: partial reductions, 8 blocks per batch.
// ---------------------------------------------------------------------------
__global__ __launch_bounds__(256) void reduce1_kernel(
    const unsigned int* __restrict__ minD, const float* __restrict__ verts,
    float* __restrict__ sums, unsigned int* __restrict__ ykmin,
    unsigned int* __restrict__ ykmax)
{
    int blk = blockIdx.x;          // 0 .. 15
    int b = blk >> 3, part = blk & 7;
    int tid = threadIdx.x;

    float s = 0.0f;
    int i0 = part * (PP / 8), i1 = i0 + (PP / 8);
    for (int i = i0 + tid; i < i1; i += 256)
        s += __uint_as_float(minD[b * PP + i]);

    float ymin = 3.4e38f, ymax = -3.4e38f;
    int v0 = part * 513, v1 = min(v0 + 513, VV);
    for (int i = v0 + tid; i < v1; i += 256) {
        float y = verts[((size_t)b * VV + i) * 3 + 1];
        ymin = fminf(ymin, y); ymax = fmaxf(ymax, y);
    }

    for (int off = 32; off > 0; off >>= 1) {
        s += __shfl_down(s, off);
        ymin = fminf(ymin, __shfl_down(ymin, off));
        ymax = fmaxf(ymax, __shfl_down(ymax, off));
    }

    __shared__ float shs[4], shmn[4], shmx[4];
    if ((tid & 63) == 0) {
        int w = tid >> 6;
        shs[w] = s; shmn[w] = ymin; shmx[w] = ymax;
    }
    __syncthreads();
    if (tid == 0) {
        float tot = shs[0], mn = shmn[0], mx = shmx[0];
        for (int w = 1; w < 4; ++w) {
            tot += shs[w];
            mn = fminf(mn, shmn[w]);
            mx = fmaxf(mx, shmx[w]);
        }
        atomicAdd(&sums[b], tot);
        atomicMin(&ykmin[b], fkey(mn));
        atomicMax(&ykmax[b], fkey(mx));
    }
}

// ---------------------------------------------------------------------------
// Kernel 3b: finish — combine per-batch partials into the scalar loss.
// ---------------------------------------------------------------------------
__global__ __launch_bounds__(64) void reduce2_kernel(
    const float* __restrict__ sums, const unsigned int* __restrict__ ykmin,
    const unsigned int* __restrict__ ykmax, float* __restrict__ out)
{
    if (threadIdx.x == 0) {
        float r = 0.0f;
        for (int b = 0; b < BB; ++b) {
            float h = funkey(ykmax[b]) - funkey(ykmin[b]);
            r += sqrtf(sums[b]) / h;
        }
        out[0] = r * 0.5f;   // mean over B=2, LOSS_WEIGHT=1
    }
}

// ---------------------------------------------------------------------------
extern "C" void kernel_launch(void* const* d_in, const int* in_sizes, int n_in,
                              void* d_out, int out_size, void* d_ws, size_t ws_size,
                              hipStream_t stream) {
    const float* pts   = (const float*)d_in[0];   // [B,P,3]
    const float* verts = (const float*)d_in[1];   // [B,V,3]
    const int*   faces = (const int*)d_in[2];     // [B,F,3]
    float* out = (float*)d_out;

    char* w = (char*)d_ws;
    float* pairrec = (float*)w;                                     // 2.75 MB
    w += (size_t)(BB * FF / 2) * (2 * NCONST) * sizeof(float);
    float4* slowrec = (float4*)w;                                   // 1.25 MB
    w += (size_t)BB * FF * SLOW_F4 * sizeof(float4);
    unsigned long long* mask = (unsigned long long*)w;              // 2 KB
    w += (size_t)(BB * FF / 64) * sizeof(unsigned long long);
    unsigned int* minD = (unsigned int*)w;                          // 64 KB
    w += (size_t)BB * PP * sizeof(unsigned int);
    float* sums = (float*)w;          w += BB * sizeof(float);
    unsigned int* ykmin = (unsigned int*)w; w += BB * sizeof(unsigned int);
    unsigned int* ykmax = (unsigned int*)w;

    precompute_kernel<<<(BB * FF + 255) / 256, 256, 0, stream>>>(
        verts, faces, pairrec, slowrec, mask, minD, sums, ykmin, ykmax);

    dim3 grid(BB * PP / PTS_PER_BLOCK, NSLICES);   // 16 x 128 = 2048 blocks
    dist_kernel<<<grid, 256, 0, stream>>>(
        pts, (const f2*)pairrec, slowrec, mask, minD);

    reduce1_kernel<<<16, 256, 0, stream>>>(minD, verts, sums, ykmin, ykmax);
    reduce2_kernel<<<1, 64, 0, stream>>>(sums, ykmin, ykmax, out);
}

// Round 12
// 194.423 us; speedup vs baseline: 1.3673x; 1.0254x over previous
//
#include <hip/hip_runtime.h>

#define EPSF 1e-12f
constexpr int BB = 2;
constexpr int PP = 8192;
constexpr int VV = 4098;
constexpr int FF = 8192;

constexpr int SLOW_F4 = 5;            // verbatim record: 5 x float4
constexpr int NCONST = 22;            // fast consts per triangle
constexpr int PTS_PER_BLOCK = 1024;   // 4 points/thread x 256 threads
constexpr int NSLICES = 128;
constexpr int CHUNK_T = FF / NSLICES; // 64 tris/block = 1 mask word

typedef float f2 __attribute__((ext_vector_type(2)));

__device__ __forceinline__ f2 vfma(f2 a, f2 b, f2 c) {
#if __has_builtin(__builtin_elementwise_fma)
    return __builtin_elementwise_fma(a, b, c);
#else
    return (f2){fmaf(a.x, b.x, c.x), fmaf(a.y, b.y, c.y)};
#endif
}
__device__ __forceinline__ f2 vmin2(f2 a, f2 b) { return __builtin_elementwise_min(a, b); }
__device__ __forceinline__ f2 vmax2(f2 a, f2 b) { return __builtin_elementwise_max(a, b); }
__device__ __forceinline__ f2 bc(float s) { return (f2){s, s}; }
__device__ __forceinline__ f2 clamp01(f2 x) { return vmin2(vmax2(x, bc(0.0f)), bc(1.0f)); }

// ---------------------------------------------------------------------------
// Kernel 1: pair-interleaved fast records + slow records + sliver mask + inits.
// Fast consts per tri (c): 0-2 ab, 3 ka1, 4-6 ac, 7 ka2, 8-10 a, 11 aa*,
// 12 ab2, 13 ac2, 14 abac, 15 bc2, 16 kbc=ab2-abac, 17 iab2, 18 iac2,
// 19 ibc2, 20 inn, 21 nn.  Interleaved per tri-PAIR (f2 = even,odd tri).
// Sliver poisoning: aa*=+inf => ap2/bp2/dAB/dAC/dBC/dIN all +inf (no 0*inf).
// ---------------------------------------------------------------------------
__global__ __launch_bounds__(256) void precompute_kernel(
    const float* __restrict__ verts, const int* __restrict__ faces,
    float* __restrict__ pairrec, float4* __restrict__ slowrec,
    unsigned long long* __restrict__ mask, unsigned int* __restrict__ minD,
    float* __restrict__ out)
{
    int idx = blockIdx.x * 256 + threadIdx.x;   // grid exactly covers BB*FF
    if (idx == 0) out[0] = 0.0f;                // reduce atomicAdds into it
    if (idx < BB * PP) minD[idx] = 0x7F800000u; // +inf
    if (idx >= BB * FF) return;

    int b = idx / FF;
    const float* vb = verts + (size_t)b * VV * 3;
    int i0 = faces[idx * 3 + 0];
    int i1 = faces[idx * 3 + 1];
    int i2 = faces[idx * 3 + 2];

    float ax = vb[i0*3+0], ay = vb[i0*3+1], az = vb[i0*3+2];
    float bx = vb[i1*3+0], by = vb[i1*3+1], bz = vb[i1*3+2];
    float cx = vb[i2*3+0], cy = vb[i2*3+1], cz = vb[i2*3+2];

    // plain fp32 subs: bit-match numpy (shared by both records)
    float abx = bx-ax, aby = by-ay, abz = bz-az;
    float acx = cx-ax, acy = cy-ay, acz = cz-az;
    float bcx = cx-bx, bcy = cy-by, bcz = cz-bz;

    {   // slow record (read only for flagged tris)
        float4* t = slowrec + (size_t)idx * SLOW_F4;
        t[0] = make_float4(ax, ay, az, abx);
        t[1] = make_float4(bx, by, bz, aby);
        t[2] = make_float4(cx, cy, cz, abz);
        t[3] = make_float4(acx, acy, acz, bcx);
        t[4] = make_float4(bcy, bcz, 0.0f, 0.0f);
    }

    float nx = aby*acz - abz*acy;
    float ny = abz*acx - abx*acz;
    float nz = abx*acy - aby*acx;

    float ka1  = abx*ax + aby*ay + abz*az;
    float ka2  = acx*ax + acy*ay + acz*az;
    float aa   = ax*ax + ay*ay + az*az;
    float abac = abx*acx + aby*acy + abz*acz;

    float ab2 = abx*abx + aby*aby + abz*abz;
    float ac2 = acx*acx + acy*acy + acz*acz;
    float bc2 = bcx*bcx + bcy*bcy + bcz*bcz;
    float nn  = nx*nx + ny*ny + nz*nz;

    float inv_ab2 = 1.0f / fmaxf(ab2, EPSF);
    float inv_ac2 = 1.0f / fmaxf(ac2, EPSF);
    float inv_bc2 = 1.0f / fmaxf(bc2, EPSF);
    float inv_nn  = 1.0f / fmaxf(nn,  EPSF);

    // sliver/degenerate classifier: sin^2(angle at a) <= 3e-2 or tiny edges
    bool slowtri = !((nn > 0.03f * (ab2 * ac2)) &&
                     (ab2 > 1e-4f) && (ac2 > 1e-4f) && (bc2 > 1e-4f));

    unsigned long long mb = __ballot(slowtri);
    if ((threadIdx.x & 63) == 0) mask[idx >> 6] = mb;

    float INF = __uint_as_float(0x7F800000u);
    float cvals[NCONST] = {
        abx, aby, abz, ka1,
        acx, acy, acz, ka2,
        ax,  ay,  az,  slowtri ? INF : aa,
        ab2, ac2, abac, bc2,
        ab2 - abac, inv_ab2, inv_ac2, inv_bc2,
        inv_nn, nn
    };
    float* pr = pairrec + (size_t)(idx >> 1) * (2 * NCONST) + (idx & 1);
#pragma unroll
    for (int c = 0; c < NCONST; ++c) pr[2*c] = cvals[c];
}

// ---------------------------------------------------------------------------
// Verbatim fp32 port (bit-exact vs numpy) — slivers only. Proven in R3.
// ---------------------------------------------------------------------------
__device__ __forceinline__ float tri_d2(
    float px, float py, float pz,
    float4 R0, float4 R1, float4 R2, float4 R3, float4 R4)
{
#pragma clang fp contract(off)
    float ax = R0.x, ay = R0.y, az = R0.z;
    float bx = R1.x, by = R1.y, bz = R1.z;
    float cx = R2.x, cy = R2.y, cz = R2.z;
    float abx = R0.w, aby = R1.w, abz = R2.w;
    float acx = R3.x, acy = R3.y, acz = R3.z;
    float bcx = R3.w, bcy = R4.x, bcz = R4.y;

    float apx = px - ax, apy = py - ay, apz = pz - az;
    float d1 = (abx*apx + aby*apy) + abz*apz;
    float d2 = (acx*apx + acy*apy) + acz*apz;
    float bpx = px - bx, bpy = py - by, bpz = pz - bz;
    float d3 = (abx*bpx + aby*bpy) + abz*bpz;
    float d4 = (acx*bpx + acy*bpy) + acz*bpz;
    float cqx = px - cx, cqy = py - cy, cqz = pz - cz;
    float d5 = (abx*cqx + aby*cqy) + abz*cqz;
    float d6 = (acx*cqx + acy*cqy) + acz*cqz;

    float va = d3*d6 - d5*d4;
    float vb = d5*d2 - d1*d6;
    float vc = d1*d4 - d3*d2;
    float u43 = d4 - d3;
    float u56 = d5 - d6;

    bool c1 = (d1 <= 0.0f) && (d2 <= 0.0f);
    bool c2 = (d3 >= 0.0f) && (d4 <= d3);
    bool c3 = (d6 >= 0.0f) && (d5 <= d6);
    bool c4 = (vc <= 0.0f) && (d1 >= 0.0f) && (d3 <= 0.0f);
    bool c5 = (vb <= 0.0f) && (d2 >= 0.0f) && (d6 <= 0.0f);
    bool c6 = (va <= 0.0f) && (u43 >= 0.0f) && (u56 >= 0.0f);

    int reg = c1 ? 0 : (c2 ? 1 : (c3 ? 2 : (c4 ? 3 : (c5 ? 4 : (c6 ? 5 : 6)))));

    float denom = fmaxf((va + vb) + vc, EPSF);
    float den1 = (reg == 3) ? fmaxf(d1 - d3, EPSF)
               : (reg == 5) ? fmaxf(u43 + u56, EPSF)
               : (reg == 6) ? denom : 1.0f;
    float num1 = (reg == 3) ? d1
               : (reg == 5) ? u43
               : (reg == 6) ? vb : 0.0f;
    float den2 = (reg == 4) ? fmaxf(d2 - d6, EPSF)
               : (reg == 6) ? denom : 1.0f;
    float num2 = (reg == 4) ? d2
               : (reg == 6) ? vc : 0.0f;
    float s = num1 / den1;
    float t = num2 / den2;

    bool useB = (reg == 1) || (reg == 5);
    bool useC = (reg == 2);
    float basex = useB ? bx : (useC ? cx : ax);
    float basey = useB ? by : (useC ? cy : ay);
    float basez = useB ? bz : (useC ? cz : az);
    bool e1bc = (reg == 5);
    float e1x = e1bc ? bcx : abx;
    float e1y = e1bc ? bcy : aby;
    float e1z = e1bc ? bcz : abz;

    float cpx = (basex + e1x*s) + acx*t;
    float cpy = (basey + e1y*s) + acy*t;
    float cpz = (basez + e1z*s) + acz*t;
    float rx = px - cpx, ry = py - cpy, rz = pz - cpz;
    return (rx*rx + ry*ry) + rz*rz;
}

// ---------------------------------------------------------------------------
// Fast-path record + eval (trimmed formulation, validated absmax 0.0 in R10).
// ---------------------------------------------------------------------------
struct Rec { f2 v[NCONST]; };

__device__ __forceinline__ Rec loadRec(const f2* p) {
    Rec r;
#pragma unroll
    for (int i = 0; i < NCONST; ++i) r.v[i] = p[i];
    return r;
}

__device__ __forceinline__ void evalRec(
    const Rec& r, const f2* X, const f2* Y, const f2* Z, const f2* W, f2* m)
{
    f2 abx=r.v[0], aby=r.v[1], abz=r.v[2], ka1=r.v[3];
    f2 acx=r.v[4], acy=r.v[5], acz=r.v[6], ka2=r.v[7];
    f2 ax=r.v[8],  ay=r.v[9],  az=r.v[10], aa=r.v[11];
    f2 ab2=r.v[12], ac2=r.v[13], abac=r.v[14], bc2=r.v[15];
    f2 kbc=r.v[16], iab2=r.v[17], iac2=r.v[18], ibc2=r.v[19];
    f2 inn=r.v[20], nn=r.v[21];

#pragma unroll
    for (int k = 0; k < 4; ++k) {
        f2 sab = vfma(abx, X[k], vfma(aby, Y[k], abz * Z[k]));
        f2 sac = vfma(acx, X[k], vfma(acy, Y[k], acz * Z[k]));
        f2 adp = vfma(ax,  X[k], vfma(ay,  Y[k], az  * Z[k]));

        f2 d1 = sab - ka1, d2 = sac - ka2;
        f2 ap2 = vfma(bc(-2.0f), adp, W[k]) + aa;   // +inf if poisoned
        f2 bp2 = vfma(bc(-2.0f), d1, ap2) + ab2;

        f2 sA = clamp01(d1 * iab2);
        f2 dAB = vfma(-sA, vfma(-sA, ab2, d1 + d1), ap2);
        f2 sC = clamp01(d2 * iac2);
        f2 dAC = vfma(-sC, vfma(-sC, ac2, d2 + d2), ap2);
        f2 u43 = (d2 - d1) + kbc;
        f2 sB = clamp01(u43 * ibc2);
        f2 dBC = vfma(-sB, vfma(-sB, bc2, u43 + u43), bp2);

        f2 v = vfma(ac2, d1, -(abac * d2));      // == reference vb
        f2 w = vfma(ab2, d2, -(abac * d1));      // == reference vc
        f2 s = v + w;
        f2 dprod = vfma(w, d2, v * d1);
        f2 dIN = vfma(-dprod, inn, ap2);         // ap2 - |inplane|^2
        f2 g = vmin2(vmin2(v, w), nn - s);       // inside iff g >= 0
        f2 dI = vfma(vmin2(g, bc(0.0f)), bc(-1e30f), dIN);

        m[k] = vmin2(m[k], vmin2(vmin2(dAB, dAC), vmin2(dBC, dI)));
    }
}

// ---------------------------------------------------------------------------
// Kernel 2: 4 points/thread, two triangles per packed op, 64 tris/block,
// ping-pong prefetch of the wave-uniform constant record (SMEM latency
// overlapped with packed compute; pairrec padded by 2 records).
// ---------------------------------------------------------------------------
__global__ __launch_bounds__(256) void dist_kernel(
    const float* __restrict__ pts, const f2* __restrict__ pair,
    const float4* __restrict__ sa, const unsigned long long* __restrict__ mask,
    unsigned int* __restrict__ minD)
{
    const float INF = __uint_as_float(0x7F800000u);
    int tid   = threadIdx.x;
    int pg    = blockIdx.x;        // 0 .. 15
    int slice = blockIdx.y;        // 0 .. 127

    int b  = pg >> 3;              // 8 point-groups per batch
    int p0 = pg * PTS_PER_BLOCK + tid;

    f2 X[4], Y[4], Z[4], W[4], m[4];
#pragma unroll
    for (int k = 0; k < 4; ++k) {
        int p = p0 + k * 256;
        X[k] = bc(pts[p*3+0]); Y[k] = bc(pts[p*3+1]); Z[k] = bc(pts[p*3+2]);
        W[k] = vfma(X[k], X[k], vfma(Y[k], Y[k], Z[k] * Z[k]));
        m[k] = bc(INF);
    }

    int t0 = b * FF + slice * CHUNK_T;
    const f2* cb = pair + (size_t)(t0 >> 1) * NCONST;

    Rec A = loadRec(cb);
#pragma unroll 1
    for (int tp = 0; tp < CHUNK_T / 2; tp += 2) {
        Rec Bx = loadRec(cb + (tp + 1) * NCONST);   // prefetch next
        evalRec(A, X, Y, Z, W, m);
        A = loadRec(cb + (tp + 2) * NCONST);        // prefetch next-next (padded)
        evalRec(Bx, X, Y, Z, W, m);
    }

    // Phase B: bit-exact eval for flagged slivers (one mask word per block)
    unsigned long long bits = mask[t0 >> 6];
    while (bits) {
        int bit = __builtin_ctzll(bits);
        bits &= bits - 1;
        const float4* sb = sa + (size_t)(t0 + bit) * SLOW_F4;
        float4 S0 = sb[0], S1 = sb[1], S2 = sb[2], S3 = sb[3], S4 = sb[4];
#pragma unroll
        for (int k = 0; k < 4; ++k)
            m[k].x = fminf(m[k].x, tri_d2(X[k].x, Y[k].x, Z[k].x, S0, S1, S2, S3, S4));
    }

    // fold halves, clamp (monotone), float-as-uint atomicMin (values >= 0)
#pragma unroll
    for (int k = 0; k < 4; ++k) {
        float r = fminf(m[k].x, m[k].y);
        atomicMin(&minD[p0 + k*256], __float_as_uint(fmaxf(r, 0.0f)));
    }
}

// ---------------------------------------------------------------------------
// Kernel 3: one block per batch (1024 threads); sum + y-extent + atomicAdd
// of this batch's loss term into out (zeroed by precompute).
// ---------------------------------------------------------------------------
__global__ __launch_bounds__(1024) void reduce_kernel(
    const unsigned int* __restrict__ minD, const float* __restrict__ verts,
    float* __restrict__ out)
{
    int b = blockIdx.x;
    int tid = threadIdx.x;

    float s = 0.0f;
    for (int i = tid; i < PP; i += 1024)
        s += __uint_as_float(minD[b * PP + i]);

    float ymin = 3.4e38f, ymax = -3.4e38f;
    for (int i = tid; i < VV; i += 1024) {
        float y = verts[((size_t)b * VV + i) * 3 + 1];
        ymin = fminf(ymin, y); ymax = fmaxf(ymax, y);
    }

    for (int off = 32; off > 0; off >>= 1) {
        s += __shfl_down(s, off);
        ymin = fminf(ymin, __shfl_down(ymin, off));
        ymax = fmaxf(ymax, __shfl_down(ymax, off));
    }

    __shared__ float shs[16], shmn[16], shmx[16];
    if ((tid & 63) == 0) {
        int w = tid >> 6;
        shs[w] = s; shmn[w] = ymin; shmx[w] = ymax;
    }
    __syncthreads();
    if (tid == 0) {
        float tot = shs[0], mn = shmn[0], mx = shmx[0];
        for (int w = 1; w < 16; ++w) {
            tot += shs[w];
            mn = fminf(mn, shmn[w]);
            mx = fmaxf(mx, shmx[w]);
        }
        atomicAdd(out, 0.5f * sqrtf(tot) / (mx - mn));  // mean over B=2
    }
}

// ---------------------------------------------------------------------------
extern "C" void kernel_launch(void* const* d_in, const int* in_sizes, int n_in,
                              void* d_out, int out_size, void* d_ws, size_t ws_size,
                              hipStream_t stream) {
    const float* pts   = (const float*)d_in[0];   // [B,P,3]
    const float* verts = (const float*)d_in[1];   // [B,V,3]
    const int*   faces = (const int*)d_in[2];     // [B,F,3]
    float* out = (float*)d_out;

    char* w = (char*)d_ws;
    float* pairrec = (float*)w;                        // 2.75 MB (+pad)
    w += ((size_t)(BB * FF / 2) + 2) * (2 * NCONST) * sizeof(float);
    float4* slowrec = (float4*)w;                      // 1.25 MB
    w += (size_t)BB * FF * SLOW_F4 * sizeof(float4);
    unsigned long long* mask = (unsigned long long*)w; // 2 KB
    w += (size_t)(BB * FF / 64) * sizeof(unsigned long long);
    unsigned int* minD = (unsigned int*)w;             // 64 KB

    precompute_kernel<<<(BB * FF + 255) / 256, 256, 0, stream>>>(
        verts, faces, pairrec, slowrec, mask, minD, out);

    dim3 grid(BB * PP / PTS_PER_BLOCK, NSLICES);   // 16 x 128 = 2048 blocks
    dist_kernel<<<grid, 256, 0, stream>>>(
        pts, (const f2*)pairrec, slowrec, mask, minD);

    reduce_kernel<<<BB, 1024, 0, stream>>>(minD, verts, out);
}